// Round 1
// baseline (929.024 us; speedup 1.0000x reference)
//
#include <hip/hip_runtime.h>
#include <math.h>

#define KNOTS 1024
#define LNE 1e-5f
#define R0F 0.5f
#define RMAXF 6.0f

__device__ __forceinline__ float hermite_(float v0, float m0, float v1, float m1, float t){
  float A = v1 - v0;
  return v0 + t*(m0 + t*((3.f*A - 2.f*m0 - m1) + t*(m0 + m1 - 2.f*A)));
}

__device__ __forceinline__ float wsum64(float v){
#pragma unroll
  for(int m=32;m>=1;m>>=1) v += __shfl_xor(v, m, 64);
  return v;
}

__global__ __launch_bounds__(256) void k_zero(int* csrOff, float* sumExp, int N){
  int i = blockIdx.x*256 + threadIdx.x;
  if(i <= N) csrOff[i] = 0;
  if(i == 0) sumExp[0] = 0.f;
}

__global__ __launch_bounds__(256) void k_weights(
    const float* ln1_g, const float* ln1_b, const float* W1, const float* b1,
    const float* ln2_g, const float* ln2_b, const float* W2, const float* b2,
    const float* ln3_g, const float* ln3_b, const float* W3, const float* b3,
    const float* resnet_p,
    float* W1gA, float* W1gB, float* W1gBot, float* W3gTop, float* W3gBot,
    float* colsum1, float* c1, float* colsum3, float* c3, float* W2g,
    float* cs1w3, float* c1w3, float* BW3, float* misc){
  int tid = threadIdx.x;
  for(int idx=tid; idx<4096; idx+=256){
    int k = idx>>6;
    W1gA[idx]   = ln1_g[k]*W1[idx];
    W1gB[idx]   = ln1_g[64+k]*W1[4096+idx];
    W3gTop[idx] = ln3_g[k]*W3[idx];
    W3gBot[idx] = ln3_g[64+k]*W3[4096+idx];
  }
  for(int idx=tid; idx<512; idx+=256) W1gBot[idx] = ln1_g[128+(idx>>6)]*W1[8192+idx];
  if(tid<128) W2g[tid] = ln2_g[tid]*W2[tid];
  if(tid<64){
    float cs=0.f, cc=0.f;
    for(int k=0;k<136;k++){ float wv = W1[k*64+tid]; cs += ln1_g[k]*wv; cc += ln1_b[k]*wv; }
    colsum1[tid] = cs; c1[tid] = cc + b1[tid];
    float cs3=0.f, cc3=0.f;
    for(int k=0;k<128;k++){ float wv = W3[k*64+tid]; cs3 += ln3_g[k]*wv; cc3 += ln3_b[k]*wv; }
    colsum3[tid] = cs3; c3[tid] = cc3 + b3[tid];
  }
  if(tid==0){
    float cs2=0.f, cc2=0.f;
    for(int k=0;k<128;k++){ cs2 += ln2_g[k]*W2[k]; cc2 += ln2_b[k]*W2[k]; }
    misc[0]=cs2; misc[1]=cc2 + b2[0];
    float p = resnet_p[0];
    float uc = 1.f/(1.f+expf(-p));
    float co = rsqrtf(uc*uc+1.f);
    misc[2] = uc*co*(1.f + co + co*co);   // 3-recycle collapse factor
  }
  __syncthreads();
  if(tid<64){
    float a=0.f, b=0.f;
    for(int k=0;k<64;k++){ float wv = W3gTop[k*64+tid]; a += colsum1[k]*wv; b += c1[k]*wv; }
    cs1w3[tid]=a; c1w3[tid]=b;
  }
  for(int idx=tid; idx<512; idx+=256){
    int kk = idx>>6, j = idx&63;
    float a=0.f;
    for(int k=0;k<64;k++) a += W1gBot[kk*64+k]*W3gTop[k*64+j];
    BW3[idx]=a;
  }
  if(tid==0){
    float a=0.f,b=0.f;
    for(int k=0;k<64;k++){ a += colsum1[k]*W2g[k]; b += c1[k]*W2g[k]; }
    misc[3]=a; misc[4]=b;
  }
  if(tid<8){
    float a=0.f;
    for(int k=0;k<64;k++) a += W1gBot[tid*64+k]*W2g[k];
    misc[8+tid]=a;
  }
}

__device__ __forceinline__ void eval_all(
    float r, const float* W1gBot, const float* BW3, const float* bw2,
    const float* F1, const float* F2, float* uL, int lane,
    float& T1, float& T13, float& T12, float& gate, float& sr, float& sq){
  float rbf[8];
  float inv_r = 1.f/r;
  float x = r*(1.f/6.f);
  float x2 = x*x;
  float x6 = x2*x2*x2;
  float th = tanhf(1.f - x6);
  float cut = th*th*th;
  float pref = 0.57735026919f*inv_r*cut;   // sqrt(2/6)
  sr=0.f; sq=0.f;
#pragma unroll
  for(int n=0;n<8;n++){
    float b = pref*sinf((float)(n+1)*0.52359877559f*r);   // pi/6
    rbf[n]=b; sr+=b; sq+=b*b;
  }
  float t1=0.f,t3=0.f,t2=0.f;
#pragma unroll
  for(int k=0;k<8;k++){
    t1 += rbf[k]*W1gBot[k*64+lane];
    t3 += rbf[k]*BW3[k*64+lane];
    t2 += rbf[k]*bw2[k];
  }
  T1=t1; T13=t3; T12=t2;
  float a0=0.f,a1=0.f,g0=0.f,g1=0.f;
#pragma unroll
  for(int k=0;k<8;k++){
    const float* row = F1 + k*256;
    float rb = rbf[k];
    a0 += rb*row[lane];      a1 += rb*row[64+lane];
    g0 += rb*row[128+lane];  g1 += rb*row[192+lane];
  }
  uL[lane]    = (a0/(1.f+expf(-a0)))*g0;
  uL[64+lane] = (a1/(1.f+expf(-a1)))*g1;
  float accv = 0.f;
  for(int i2=0;i2<128;i2++) accv += uL[i2]*F2[i2*64+lane];
  gate = 1.f/(1.f+expf(-accv));
}

__global__ __launch_bounds__(256) void k_tables(
    const float* W1gBot, const float* BW3, const float* misc,
    const float* F1, const float* F2,
    float* tabT1, float* tabT13, float* tabG, float* tabS){
  __shared__ __align__(16) float u[4][128];
  int lane = threadIdx.x&63, w = threadIdx.x>>6;
  int knot = blockIdx.x*4 + w;
  if(knot > KNOTS) return;
  const float H = (RMAXF-R0F)/KNOTS;
  float r = R0F + knot*H;
  const float dh = 1e-3f;
  const float* bw2 = misc+8;
  float T1c,T13c,T12c,Gc,SRc,SQc, T1p,T13p,T12p,Gp,SRp,SQp, T1m,T13m,T12m,Gm,SRm,SQm;
  eval_all(r,    W1gBot,BW3,bw2,F1,F2,u[w],lane, T1c,T13c,T12c,Gc,SRc,SQc);
  eval_all(r+dh, W1gBot,BW3,bw2,F1,F2,u[w],lane, T1p,T13p,T12p,Gp,SRp,SQp);
  eval_all(r-dh, W1gBot,BW3,bw2,F1,F2,u[w],lane, T1m,T13m,T12m,Gm,SRm,SQm);
  float sc = H/(2.f*dh);
  ((float2*)tabT1)[(size_t)knot*64+lane]  = make_float2(T1c, (T1p-T1m)*sc);
  ((float2*)tabT13)[(size_t)knot*64+lane] = make_float2(T13c,(T13p-T13m)*sc);
  ((float2*)tabG)[(size_t)knot*64+lane]   = make_float2(Gc,  (Gp-Gm)*sc);
  if(lane==0){
    float* d = tabS + (size_t)knot*8;
    d[0]=SRc; d[1]=(SRp-SRm)*sc; d[2]=SQc; d[3]=(SQp-SQm)*sc;
    d[4]=T12c; d[5]=(T12p-T12m)*sc; d[6]=0.f; d[7]=0.f;
  }
}

__global__ __launch_bounds__(256) void k_node1(
    const float* attrs, const float* W1gA, const float* W1gB, const float* W2g,
    float* P, float* Q, float* nS, float* nSQ, float* nT, int N){
  int v = (blockIdx.x*256+threadIdx.x)>>6;
  int lane = threadIdx.x&63;
  if(v>=N) return;
  const float* av = attrs + (size_t)v*64;
  float al = av[lane];
  float s = wsum64(al), sq = wsum64(al*al), t = wsum64(al*W2g[64+lane]);
  float p=0.f, q=0.f;
#pragma unroll 8
  for(int k=0;k<64;k++){
    float a = av[k];
    p += a*W1gA[k*64+lane];
    q += a*W1gB[k*64+lane];
  }
  P[(size_t)v*64+lane]=p; Q[(size_t)v*64+lane]=q;
  if(lane==0){ nS[v]=s; nSQ[v]=sq; nT[v]=t; }
}

__global__ __launch_bounds__(256) void k_node1b(
    const float* P, const float* Q, const float* W3gTop, const float* W2g,
    float* PW3, float* QW3, float* PW2s, float* QW2s, int N){
  __shared__ __align__(16) float sb[4][128];
  int v = (blockIdx.x*256+threadIdx.x)>>6;
  int lane = threadIdx.x&63, w = (threadIdx.x>>6)&3;
  if(v>=N) return;
  float pl = P[(size_t)v*64+lane], ql = Q[(size_t)v*64+lane];
  float pw2 = wsum64(pl*W2g[lane]);
  float qw2 = wsum64(ql*W2g[lane]);
  sb[w][lane]=pl; sb[w][64+lane]=ql;
  float ap=0.f, aq=0.f;
  const float4* pv = (const float4*)(&sb[w][0]);
  const float4* qv = (const float4*)(&sb[w][64]);
#pragma unroll
  for(int kk=0;kk<16;kk++){
    float4 xp = pv[kk], xq = qv[kk];
    const float* wc = W3gTop + kk*256 + lane;
    ap += xp.x*wc[0] + xp.y*wc[64] + xp.z*wc[128] + xp.w*wc[192];
    aq += xq.x*wc[0] + xq.y*wc[64] + xq.z*wc[128] + xq.w*wc[192];
  }
  PW3[(size_t)v*64+lane]=ap; QW3[(size_t)v*64+lane]=aq;
  if(lane==0){ PW2s[v]=pw2; QW2s[v]=qw2; }
}

__global__ __launch_bounds__(256) void k_hist(const int* ei, int* cnt, int N, int E){
  int e = blockIdx.x*256+threadIdx.x;
  if(e<E){ int c = ei[e]; c = min(max(c,0),N-1); atomicAdd(&cnt[c],1); }
}

__global__ __launch_bounds__(1024) void k_scan(int* csrOff, int* csrCur, int N){
  __shared__ int part[1024];
  int tid = threadIdx.x;
  int chunk = (N + 1023)/1024;
  int s = tid*chunk;
  int e = min(s+chunk, N);
  int sum = 0;
  for(int i=s;i<e;i++) sum += csrOff[i];
  part[tid]=sum;
  __syncthreads();
  for(int d=1; d<1024; d<<=1){
    int v = part[tid];
    int add = (tid>=d)? part[tid-d] : 0;
    __syncthreads();
    part[tid] = v+add;
    __syncthreads();
  }
  int run = (tid==0)? 0 : part[tid-1];
  for(int i=s;i<e;i++){
    int c = csrOff[i];
    csrOff[i]=run; csrCur[i]=run;
    run += c;
  }
  if(tid==1023) csrOff[N] = part[1023];
}

__global__ __launch_bounds__(256) void k_fill(const int* ei, int* cur, int* edgeIds, int N, int E){
  int e = blockIdx.x*256+threadIdx.x;
  if(e<E){
    int c = ei[e]; c = min(max(c,0),N-1);
    int pos = atomicAdd(&cur[c],1);
    if(pos>=0 && pos<E) edgeIds[pos]=e;
  }
}

__global__ __launch_bounds__(256) void k_pool(
    const int* ei, const float* elen, const int* csrOff, const int* edgeIds,
    const float* P, const float* Q, const float* nS, const float* nSQ, const float* nT,
    const float* PW2s, const float* QW2s,
    const float* colsum1, const float* c1, const float* misc,
    const float* tabT1, const float* tabS,
    float* pooledRaw, float* sumExp, int N, int E){
  int v = (blockIdx.x*256 + threadIdx.x)>>6;
  int lane = threadIdx.x&63;
  if(v >= N) return;
  float Pl = P[(size_t)v*64+lane];
  float colg1 = colsum1[lane], c1l = c1[lane];
  float sv = nS[v], sqv = nSQ[v], tv = nT[v], pw2v = PW2s[v];
  float cs2 = misc[0], c2v = misc[1], csw2 = misc[3], cw2 = misc[4];
  const float invH = (float)KNOTS/(RMAXF-R0F);
  int st = csrOff[v], ed = csrOff[v+1];
  float acc = 0.f, accE = 0.f;
  int nb_nx = 0; float r_nx = R0F;
  if(st < ed){
    int e0 = edgeIds[st];
    nb_nx = ei[E+e0]; r_nx = elen[e0];
  }
  for(int idx=st; idx<ed; idx++){
    int nb = min(max(nb_nx,0),N-1);
    float r = r_nx;
    if(idx+1 < ed){
      int e2 = edgeIds[idx+1];
      nb_nx = ei[E+e2]; r_nx = elen[e2];
    }
    float uu = (r-R0F)*invH;
    int ti = (int)uu; ti = min(max(ti,0), KNOTS-1);
    float tt = uu - (float)ti;
    size_t tb0 = (size_t)ti*64+lane, tb1 = tb0+64;
    float2 t1a = ((const float2*)tabT1)[tb0], t1b = ((const float2*)tabT1)[tb1];
    const float* s0 = tabS + (size_t)ti*8;
    float4 sca = *(const float4*)s0;
    float4 scb = *(const float4*)(s0+8);
    float2 twa = *(const float2*)(s0+4);
    float2 twb = *(const float2*)(s0+12);
    float T1  = hermite_(t1a.x,t1a.y,t1b.x,t1b.y,tt);
    float srb = hermite_(sca.x,sca.y,scb.x,scb.y,tt);
    float sqb = hermite_(sca.z,sca.w,scb.z,scb.w,tt);
    float t1w2= hermite_(twa.x,twa.y,twb.x,twb.y,tt);
    float Ql = Q[(size_t)nb*64+lane];
    float sumx = sv + nS[nb] + srb;
    float ssx  = sqv + nSQ[nb] + sqb;
    float m = sumx*(1.f/136.f);
    float var = ssx*(1.f/136.f) - m*m;
    float rs = rsqrtf(var + LNE);
    float ef = rs*(Pl + Ql + T1 - m*colg1) + c1l;
    float r0 = ef, r1 = ef*ef;
#pragma unroll
    for(int msk=32; msk>=1; msk>>=1){ r0 += __shfl_xor(r0,msk,64); r1 += __shfl_xor(r1,msk,64); }
    float sw = rs*(pw2v + QW2s[nb] + t1w2 - m*csw2) + cw2;
    float m2 = (r0 + sv)*(1.f/128.f);
    float var2 = (r1 + sqv)*(1.f/128.f) - m2*m2;
    float rs2 = rsqrtf(var2 + LNE);
    float score = rs2*(sw + tv - m2*cs2) + c2v;
    float eev = expf(score);
    acc += eev*ef; accE += eev;
  }
  pooledRaw[(size_t)v*64+lane] = acc;
  if(lane==0) atomicAdd(sumExp, accE);
}

__global__ __launch_bounds__(256) void k_node2(
    const float* pooledRaw, const float* sumExp, const float* W3gBot,
    float* R, float* psum, float* psumsq, int N){
  __shared__ __align__(16) float sb[4][64];
  int v = (blockIdx.x*256+threadIdx.x)>>6;
  int lane = threadIdx.x&63, w = (threadIdx.x>>6)&3;
  if(v>=N) return;
  float inv = 1.f/sumExp[0];
  float pl = pooledRaw[(size_t)v*64+lane]*inv;
  float s = wsum64(pl), sq = wsum64(pl*pl);
  sb[w][lane] = pl;
  float acc = 0.f;
  const float4* pv = (const float4*)(&sb[w][0]);
#pragma unroll
  for(int kk=0;kk<16;kk++){
    float4 x = pv[kk];
    const float* wc = W3gBot + kk*256 + lane;
    acc += x.x*wc[0] + x.y*wc[64] + x.z*wc[128] + x.w*wc[192];
  }
  R[(size_t)v*64+lane] = acc;
  if(lane==0){ psum[v]=s; psumsq[v]=sq; }
}

__global__ __launch_bounds__(256) void k_final(
    const int* ei, const float* elen,
    const float* P, const float* Q, const float* PW3, const float* QW3, const float* R,
    const float* nS, const float* nSQ, const float* psum, const float* psumsq,
    const float* colsum1, const float* c1, const float* cs1w3, const float* c1w3,
    const float* colsum3, const float* c3, const float* misc,
    const float* tabT1, const float* tabT13, const float* tabG, const float* tabS,
    float* out, int N, int E){
  int w = threadIdx.x>>6, lane = threadIdx.x&63;
  float colg1 = colsum1[lane], c1l = c1[lane];
  float csw3 = cs1w3[lane], cw3 = c1w3[lane];
  float col3 = colsum3[lane], c3l = c3[lane];
  float SC = misc[2];
  const float invH = (float)KNOTS/(RMAXF-R0F);
  int eb = (blockIdx.x*4 + w)*16;
  for(int i=0;i<16;i++){
    int e = eb+i;
    if(e >= E) return;
    int ec = ei[e];   ec = min(max(ec,0),N-1);
    int en = ei[E+e]; en = min(max(en,0),N-1);
    float r = elen[e];
    float uu = (r-R0F)*invH;
    int ti = (int)uu; ti = min(max(ti,0), KNOTS-1);
    float tt = uu - (float)ti;
    size_t tb0 = (size_t)ti*64 + lane, tb1 = tb0 + 64;
    float2 t1a = ((const float2*)tabT1)[tb0],  t1b = ((const float2*)tabT1)[tb1];
    float2 t3a = ((const float2*)tabT13)[tb0], t3b = ((const float2*)tabT13)[tb1];
    float2 gaa = ((const float2*)tabG)[tb0],   gab = ((const float2*)tabG)[tb1];
    const float* s0 = tabS + (size_t)ti*8;
    float4 sca = *(const float4*)s0;
    float4 scb = *(const float4*)(s0+8);
    float T1  = hermite_(t1a.x,t1a.y,t1b.x,t1b.y,tt);
    float T13 = hermite_(t3a.x,t3a.y,t3b.x,t3b.y,tt);
    float gate= hermite_(gaa.x,gaa.y,gab.x,gab.y,tt);
    float srb = hermite_(sca.x,sca.y,scb.x,scb.y,tt);
    float sqb = hermite_(sca.z,sca.w,scb.z,scb.w,tt);
    size_t bc = (size_t)ec*64 + lane, bn = (size_t)en*64 + lane;
    float Pl = P[bc], Ql = Q[bn], P3 = PW3[bc], Q3 = QW3[bn], Rl = R[bc];
    float sumx = nS[ec] + nS[en] + srb;
    float ssx  = nSQ[ec] + nSQ[en] + sqb;
    float m = sumx*(1.f/136.f);
    float var = ssx*(1.f/136.f) - m*m;
    float rs = rsqrtf(var + LNE);
    float ef = rs*(Pl + Ql + T1 - m*colg1) + c1l;
    float r0 = ef, r1 = ef*ef;
#pragma unroll
    for(int msk=32; msk>=1; msk>>=1){ r0 += __shfl_xor(r0,msk,64); r1 += __shfl_xor(r1,msk,64); }
    float m3 = (r0 + psum[ec])*(1.f/128.f);
    float var3 = (r1 + psumsq[ec])*(1.f/128.f) - m3*m3;
    float rs3 = rsqrtf(var3 + LNE);
    float efdot = rs*(P3 + Q3 + T13 - m*csw3) + cw3;
    float upd = rs3*(efdot + Rl - m3*col3) + c3l;
    out[(size_t)e*64 + lane] = SC*upd*gate;
  }
}

extern "C" void kernel_launch(void* const* d_in, const int* in_sizes, int n_in,
                              void* d_out, int out_size, void* d_ws, size_t ws_size,
                              hipStream_t stream){
  const int*   ei    = (const int*)  d_in[0];
  const float* elen  = (const float*)d_in[1];
  const float* attrs = (const float*)d_in[2];
  const float* ln1_g = (const float*)d_in[3];
  const float* ln1_b = (const float*)d_in[4];
  const float* W1    = (const float*)d_in[5];
  const float* b1    = (const float*)d_in[6];
  const float* ln2_g = (const float*)d_in[7];
  const float* ln2_b = (const float*)d_in[8];
  const float* W2    = (const float*)d_in[9];
  const float* b2    = (const float*)d_in[10];
  const float* ln3_g = (const float*)d_in[11];
  const float* ln3_b = (const float*)d_in[12];
  const float* W3    = (const float*)d_in[13];
  const float* b3    = (const float*)d_in[14];
  const float* F1    = (const float*)d_in[15];
  const float* F2    = (const float*)d_in[16];
  const float* resp  = (const float*)d_in[17];
  const int E = in_sizes[1];
  const int N = in_sizes[2]/64;
  float* ws = (float*)d_ws;
  size_t o = 0;
  auto A = [&](size_t n){ size_t rr = o; o += (n + 63) & ~(size_t)63; return rr; };
  float* P      = ws + A((size_t)N*64);
  float* Q      = ws + A((size_t)N*64);
  float* PW3    = ws + A((size_t)N*64);
  float* QW3    = ws + A((size_t)N*64);
  float* R      = ws + A((size_t)N*64);
  float* pooled = ws + A((size_t)N*64);
  float* nS     = ws + A(N);
  float* nSQ    = ws + A(N);
  float* nT     = ws + A(N);
  float* PW2s   = ws + A(N);
  float* QW2s   = ws + A(N);
  float* psum   = ws + A(N);
  float* psq    = ws + A(N);
  float* W1gA   = ws + A(4096);
  float* W1gB   = ws + A(4096);
  float* W1gBot = ws + A(512);
  float* W3gTop = ws + A(4096);
  float* W3gBot = ws + A(4096);
  float* BW3    = ws + A(512);
  float* colsum1= ws + A(64);
  float* c1     = ws + A(64);
  float* cs1w3  = ws + A(64);
  float* c1w3   = ws + A(64);
  float* colsum3= ws + A(64);
  float* c3     = ws + A(64);
  float* W2g    = ws + A(128);
  float* misc   = ws + A(64);
  float* tabT1  = ws + A((size_t)(KNOTS+1)*128);
  float* tabT13 = ws + A((size_t)(KNOTS+1)*128);
  float* tabG   = ws + A((size_t)(KNOTS+1)*128);
  float* tabS   = ws + A((size_t)(KNOTS+1)*8);
  float* sumExp = ws + A(64);
  int* csrOff   = (int*)(ws + A((size_t)N+1));
  int* csrCur   = (int*)(ws + A((size_t)N));
  int* edgeIds  = (int*)(ws + A((size_t)E));
  (void)ws_size; (void)out_size; (void)n_in;
  float* out = (float*)d_out;

  int nb4 = (N+3)/4;
  k_zero<<<(N+2+255)/256, 256, 0, stream>>>(csrOff, sumExp, N);
  k_weights<<<1,256,0,stream>>>(ln1_g,ln1_b,W1,b1,ln2_g,ln2_b,W2,b2,ln3_g,ln3_b,W3,b3,resp,
      W1gA,W1gB,W1gBot,W3gTop,W3gBot,colsum1,c1,colsum3,c3,W2g,cs1w3,c1w3,BW3,misc);
  k_tables<<<(KNOTS+4)/4, 256, 0, stream>>>(W1gBot,BW3,misc,F1,F2,tabT1,tabT13,tabG,tabS);
  k_node1<<<nb4,256,0,stream>>>(attrs,W1gA,W1gB,W2g,P,Q,nS,nSQ,nT,N);
  k_node1b<<<nb4,256,0,stream>>>(P,Q,W3gTop,W2g,PW3,QW3,PW2s,QW2s,N);
  k_hist<<<(E+255)/256,256,0,stream>>>(ei,csrOff,N,E);
  k_scan<<<1,1024,0,stream>>>(csrOff,csrCur,N);
  k_fill<<<(E+255)/256,256,0,stream>>>(ei,csrCur,edgeIds,N,E);
  k_pool<<<nb4,256,0,stream>>>(ei,elen,csrOff,edgeIds,P,Q,nS,nSQ,nT,PW2s,QW2s,colsum1,c1,misc,tabT1,tabS,pooled,sumExp,N,E);
  k_node2<<<nb4,256,0,stream>>>(pooled,sumExp,W3gBot,R,psum,psq,N);
  k_final<<<(E+63)/64,256,0,stream>>>(ei,elen,P,Q,PW3,QW3,R,nS,nSQ,psum,psq,colsum1,c1,cs1w3,c1w3,colsum3,c3,misc,tabT1,tabT13,tabG,tabS,out,N,E);
}